// Round 1
// baseline (365.328 us; speedup 1.0000x reference)
//
#include <hip/hip_runtime.h>
#include <math.h>

#define W_IN   16384
#define FLT    32
#define W_OUT  (W_IN - FLT + 1)      // 16353
#define TILE_OUT 1024
#define TILE_IN  (TILE_OUT + FLT)    // 1056
#define R      4
#define NT     256
#define N_TILES 16                   // 16*1024 = 16384 >= 16353
#define OUT_SCALE 0.17782794100389228f   // sqrt(10^(-15/10))

__device__ __forceinline__ float fast_tanh(float z) {
    // tanh(z) = 1 - 2/(exp(2z)+1); safe at +-inf (-> +-1)
    float e = __expf(2.0f * z);
    return 1.0f - 2.0f / (e + 1.0f);
}

__global__ __launch_bounds__(NT)
void fused_env_mlp_fir_kernel(const float* __restrict__ xr,
                              const float* __restrict__ xi,
                              const float* __restrict__ w1,   // [8]  1->8
                              const float* __restrict__ w2,   // [8]  8->1
                              const float* __restrict__ wlr,  // [32]
                              const float* __restrict__ wli,  // [32]
                              float* __restrict__ out)        // [1024, 16353, 2]
{
    __shared__ float sxr[TILE_IN];
    __shared__ float sxi[TILE_IN];

    const int bid    = blockIdx.x;
    const int row    = bid >> 4;        // 0..1023 (b*64+h)
    const int tile   = bid & 15;        // 0..15
    const int tstart = tile * TILE_OUT;
    const int tid    = threadIdx.x;

    const float* __restrict__ xr_row = xr + (size_t)row * W_IN;
    const float* __restrict__ xi_row = xi + (size_t)row * W_IN;

    // NL weights: uniform loads -> expect SGPR residency
    float c1[8], c2[8];
#pragma unroll
    for (int j = 0; j < 8; ++j) { c1[j] = w1[j]; c2[j] = w2[j]; }

    // ---- Stage 1: global -> NL -> LDS (264 float4 tasks) ----
    for (int i4 = tid; i4 < TILE_IN / 4; i4 += NT) {
        const int g = tstart + i4 * 4;
        float4 vr, vi;
        if (g + 3 < W_IN) {
            vr = *(const float4*)(xr_row + g);
            vi = *(const float4*)(xi_row + g);
        } else {
            vr = make_float4(0.f, 0.f, 0.f, 0.f);
            vi = make_float4(0.f, 0.f, 0.f, 0.f);
        }
        float ar[4] = {vr.x, vr.y, vr.z, vr.w};
        float ai[4] = {vi.x, vi.y, vi.z, vi.w};
        float orr[4], oii[4];
#pragma unroll
        for (int e = 0; e < 4; ++e) {
            const float a = ar[e], b = ai[e];
            const float s   = fmaxf(fmaf(a, a, b * b), 1e-30f);
            const float mag = sqrtf(s);
            float h = 0.f;
#pragma unroll
            for (int j = 0; j < 8; ++j)
                h = fmaf(c2[j], fast_tanh(mag * c1[j]), h);
            const float scale = h / mag;   // cos/sin(atan2) folded in
            orr[e] = a * scale;
            oii[e] = b * scale;
        }
        *(float4*)(sxr + i4 * 4) = make_float4(orr[0], orr[1], orr[2], orr[3]);
        *(float4*)(sxi + i4 * 4) = make_float4(oii[0], oii[1], oii[2], oii[3]);
    }

    __syncthreads();

    // ---- Stage 2: 32-tap complex FIR, R=4 outputs/thread ----
    // FIR weights: uniform -> SGPR; FMAs become s*v+v
    float cwr[FLT], cwi[FLT];
#pragma unroll
    for (int k = 0; k < FLT; ++k) { cwr[k] = wlr[k]; cwi[k] = wli[k]; }

    const int base = tid * R;            // 0..1020, 16B-aligned window start
    float xwr[36], xwi[36];              // need 35, load 36 (9 x float4)
#pragma unroll
    for (int m = 0; m < 9; ++m) {
        float4 t4 = *(const float4*)(sxr + base + m * 4);
        xwr[m * 4 + 0] = t4.x; xwr[m * 4 + 1] = t4.y;
        xwr[m * 4 + 2] = t4.z; xwr[m * 4 + 3] = t4.w;
        float4 u4 = *(const float4*)(sxi + base + m * 4);
        xwi[m * 4 + 0] = u4.x; xwi[m * 4 + 1] = u4.y;
        xwi[m * 4 + 2] = u4.z; xwi[m * 4 + 3] = u4.w;
    }

    float accr[R] = {0.f, 0.f, 0.f, 0.f};
    float acci[R] = {0.f, 0.f, 0.f, 0.f};
#pragma unroll
    for (int k = 0; k < FLT; ++k) {
        const float wr = cwr[k];
        const float wi = cwi[k];
#pragma unroll
        for (int r = 0; r < R; ++r) {
            const float a = xwr[r + k];
            const float b = xwi[r + k];
            accr[r] = fmaf(a,  wr, accr[r]);
            accr[r] = fmaf(b, -wi, accr[r]);
            acci[r] = fmaf(b,  wr, acci[r]);
            acci[r] = fmaf(a,  wi, acci[r]);
        }
    }

    float* __restrict__ out_row = out + (size_t)row * (W_OUT * 2);
#pragma unroll
    for (int r = 0; r < R; ++r) {
        const int w = tstart + base + r;
        if (w < W_OUT) {
            float2 v = make_float2(OUT_SCALE * accr[r], OUT_SCALE * acci[r]);
            *(float2*)(out_row + (size_t)w * 2) = v;   // row base only 8B-aligned
        }
    }
}

extern "C" void kernel_launch(void* const* d_in, const int* in_sizes, int n_in,
                              void* d_out, int out_size, void* d_ws, size_t ws_size,
                              hipStream_t stream) {
    const float* xr  = (const float*)d_in[0];
    const float* xi  = (const float*)d_in[1];
    const float* w1  = (const float*)d_in[2];
    const float* w2  = (const float*)d_in[3];
    const float* wlr = (const float*)d_in[4];
    const float* wli = (const float*)d_in[5];
    float* out = (float*)d_out;

    const int rows = 16 * 64;                    // B*H = 1024
    dim3 grid(rows * N_TILES);                   // 16384 blocks
    dim3 block(NT);
    fused_env_mlp_fir_kernel<<<grid, block, 0, stream>>>(xr, xi, w1, w2, wlr, wli, out);
}